// Round 1
// baseline (518.797 us; speedup 1.0000x reference)
//
#include <hip/hip_runtime.h>
#include <math.h>

#define DDIM 2048
#define NDIM 8192
#define NTRI8 36   // lower-triangle 256x256 tiles of the 2048x2048 G (8x8 grid)

typedef _Float16 f16;
typedef _Float16 f16x8 __attribute__((ext_vector_type(8)));
typedef _Float16 f16x4 __attribute__((ext_vector_type(4)));
typedef float    f32x4 __attribute__((ext_vector_type(4)));

#define MFMA16(a, b, c) __builtin_amdgcn_mfma_f32_16x16x32_f16(a, b, c, 0, 0, 0)

__device__ __forceinline__ void gload_lds16(const f16* g, f16* l) {
    __builtin_amdgcn_global_load_lds(
        (__attribute__((address_space(1))) const void*)g,
        (__attribute__((address_space(3))) void*)l, 16, 0, 0);
}

// raw barrier (NOT __syncthreads: avoids compiler-inserted vmcnt(0) drain)
#define SBAR() do { __builtin_amdgcn_sched_barrier(0); \
                    __builtin_amdgcn_s_barrier();      \
                    __builtin_amdgcn_sched_barrier(0); } while (0)
#define VMCNT0() asm volatile("s_waitcnt vmcnt(0)" ::: "memory")
#define VMCNT4() asm volatile("s_waitcnt vmcnt(4)" ::: "memory")
#define VMCNT6() asm volatile("s_waitcnt vmcnt(6)" ::: "memory")

// bijective XCD-chunk swizzle (m204): n may be non-multiple of 8
__device__ __forceinline__ int xcd_swz(int lin, int n) {
    const int xcd = lin & 7, pos = lin >> 3;
    const int q = n >> 3, r = n & 7;
    return (xcd < r ? xcd * (q + 1) : r * (q + 1) + (xcd - r) * q) + pos;
}

// ---------------------------------------------------------------------------
// T2 bank-conflict swizzle for the [256 rows][32 f16] LDS unit (64 B rows).
// 16-B k-slot j of row R lives at slot j ^ ((R>>1)&3). Applied BOTH on the
// global source (stage) and on the read -> involution, rule #21 satisfied.
// ---------------------------------------------------------------------------
__device__ __forceinline__ int swz(int R, int fo8) {
    return R * 32 + (fo8 ^ (((R >> 1) & 3) << 3));
}

// stage one 16 KiB unit (256 rows x 32 k-elems, f16) global -> LDS.
// LDS dest linear (gload_lds requirement); source k-slot pre-swizzled.
__device__ __forceinline__ void stage_unit(
    const f16* __restrict__ g, int grow0, size_t kelem, int Ktot,
    f16* ldsbase, int tid)
{
#pragma unroll
    for (int i = 0; i < 2; ++i) {
        const int c = tid + i * 512;
        const int row  = c >> 2;
        const int slot = (c & 3) ^ ((c >> 3) & 3);   // (c&3) ^ ((row>>1)&3)
        gload_lds16(g + (size_t)(grow0 + row) * Ktot + kelem + slot * 8,
                    ldsbase + c * 8);
    }
}

// ---------------------------------------------------------------------------
// K2: 256x256 FUSED split-fp16 NT GEMM, 3-phase counted-vmcnt schedule.
//   C_z += Ah Bh^T + Ah Bl^T + Al Bh^T   over the block's K-chunk.
// BK=32; units {Ah,Al,Bh,Bl} of 16 KiB; LDS = 2 buf x 64 KiB = 128 KiB.
// 8 waves (2M x 4N), per-wave 128x64 output, acc 8x4 fragments.
// Phases/K-tile (register-reuse ordering; 24 ds_reads vs old 32):
//   PA: read ah[8]+bh[4] (12), stage Bh(u+1)+Ah(u+1), MFMA 32 (HH)
//   PB: read bl[4]       (4),  stage Bl(u+1),         MFMA 32 (ah x bl, reuse)
//   PC: read al[8]       (8),  stage Al(u+1),         MFMA 32 (al x bh, reuse)
// Waits (8 in flight steady-state, per-thread 2 vmem ops/unit):
//   PA-end vmcnt(6) [Bl(u) ready], PB-end vmcnt(6) [Al(u) ready],
//   PC-end vmcnt(4) [Bh/Ah(u+1) ready]; last iter: vmcnt(0) at PA-end.
// ---------------------------------------------------------------------------
template <bool TRI>
__global__ __launch_bounds__(512, 2) void gemm8_split(
    const f16* __restrict__ Ah_g, const f16* __restrict__ Al_g,
    const f16* __restrict__ Bh_g, const f16* __restrict__ Bl_g,
    float* __restrict__ C, int Mrows, int Ncols, int Ktot, int Kchunk)
{
    __shared__ f16 lds[65536];   // 128 KiB

    const int tid  = threadIdx.x;
    const int lane = tid & 63;
    const int w    = tid >> 6;
    const int wr   = w >> 2;          // 0..1
    const int wc   = w & 3;           // 0..3
    const int ln15 = lane & 15;
    const int fo8  = (lane >> 4) * 8;

    int row0, col0, nkt;
    size_t kbeg;
    if constexpr (TRI) {
        const int t = xcd_swz(blockIdx.x, NTRI8);
        int i = 0;
        while ((i + 1) * (i + 2) / 2 <= t) ++i;
        const int j = t - i * (i + 1) / 2;
        row0 = i * 256; col0 = j * 256;
        const int z = blockIdx.z;                       // 0..6, uneven chunks
        const int kb_u = z * 37 - (z > 4 ? z - 4 : 0);  // 37,37,37,37,36,36,36
        nkt = (z < 4) ? 37 : 36;
        kbeg = (size_t)kb_u * 32;
        C += ((size_t)z * NTRI8 + t) * (256 * 256);     // compact partial
    } else {
        const int s = xcd_swz(blockIdx.y * gridDim.x + blockIdx.x,
                              gridDim.x * gridDim.y);
        row0 = (s / gridDim.x) * 256;
        col0 = (s % gridDim.x) * 256;
        nkt  = Kchunk / 32;
        kbeg = (size_t)blockIdx.z * Kchunk;
        C += (size_t)blockIdx.z * Mrows * Ncols;
    }

    f32x4 acc[8][4] = {};

    // prologue: tile0's 4 units; drain; barrier
    stage_unit(Ah_g, row0, kbeg, Ktot, lds + 0,     tid);
    stage_unit(Al_g, row0, kbeg, Ktot, lds + 8192,  tid);
    stage_unit(Bh_g, col0, kbeg, Ktot, lds + 16384, tid);
    stage_unit(Bl_g, col0, kbeg, Ktot, lds + 24576, tid);
    VMCNT0();
    SBAR();

    for (int u = 0; u < nkt; ++u) {
        const int cur = (u & 1) * 32768, nxt = ((u + 1) & 1) * 32768;
        const size_t ku = kbeg + (size_t)u * 32;
        f16x8 ah[8], bh[4];

        // ---- PA: HH, all n ----
#pragma unroll
        for (int m = 0; m < 8; ++m)
            ah[m] = *(const f16x8*)&lds[cur + swz(wr * 128 + m * 16 + ln15, fo8)];
#pragma unroll
        for (int n = 0; n < 4; ++n)
            bh[n] = *(const f16x8*)&lds[cur + 16384 + swz(wc * 64 + n * 16 + ln15, fo8)];
        if (u + 1 < nkt) {
            stage_unit(Bh_g, col0, ku + 32, Ktot, lds + nxt + 16384, tid);
            stage_unit(Ah_g, row0, ku + 32, Ktot, lds + nxt + 0, tid);
        }
        SBAR();
        __builtin_amdgcn_s_setprio(1);
#pragma unroll
        for (int m = 0; m < 8; ++m)
#pragma unroll
            for (int n = 0; n < 4; ++n)
                acc[m][n] = MFMA16(ah[m], bh[n], acc[m][n]);
        __builtin_amdgcn_s_setprio(0);
        if (u == nkt - 1) { VMCNT0(); } else { VMCNT6(); }
        SBAR();

        // ---- PB: HL, all n (ah reused in registers) ----
        {
            f16x8 bl[4];
#pragma unroll
            for (int n = 0; n < 4; ++n)
                bl[n] = *(const f16x8*)&lds[cur + 24576 + swz(wc * 64 + n * 16 + ln15, fo8)];
            if (u + 1 < nkt) stage_unit(Bl_g, col0, ku + 32, Ktot, lds + nxt + 24576, tid);
            SBAR();
            __builtin_amdgcn_s_setprio(1);
#pragma unroll
            for (int m = 0; m < 8; ++m)
#pragma unroll
                for (int n = 0; n < 4; ++n)
                    acc[m][n] = MFMA16(ah[m], bl[n], acc[m][n]);
            __builtin_amdgcn_s_setprio(0);
        }
        if (u + 1 < nkt) { VMCNT6(); }
        SBAR();

        // ---- PC: LH, all n (bh reused in registers) ----
        {
            f16x8 al[8];
#pragma unroll
            for (int m = 0; m < 8; ++m)
                al[m] = *(const f16x8*)&lds[cur + 8192 + swz(wr * 128 + m * 16 + ln15, fo8)];
            if (u + 1 < nkt) stage_unit(Al_g, row0, ku + 32, Ktot, lds + nxt + 8192, tid);
            SBAR();
            __builtin_amdgcn_s_setprio(1);
#pragma unroll
            for (int m = 0; m < 8; ++m)
#pragma unroll
                for (int n = 0; n < 4; ++n)
                    acc[m][n] = MFMA16(al[m], bh[n], acc[m][n]);
            __builtin_amdgcn_s_setprio(0);
        }
        if (u + 1 < nkt) { VMCNT4(); }
        SBAR();
    }

    // epilogue: C/D layout col=lane&15, row=(lane>>4)*4+reg [m89-verified]
    const int rsub = (lane >> 4) * 4;
#pragma unroll
    for (int m = 0; m < 8; ++m)
#pragma unroll
        for (int n = 0; n < 4; ++n)
#pragma unroll
            for (int r = 0; r < 4; ++r) {
                const int cr = wr * 128 + m * 16 + rsub + r;
                const int cc = wc * 64 + n * 16 + ln15;
                if constexpr (TRI)
                    C[(size_t)cr * 256 + cc] = acc[m][n][r];
                else
                    C[(size_t)(row0 + cr) * Ncols + col0 + cc] = acc[m][n][r];
            }
}

// ---------------------------------------------------------------------------
// K1: 256x256 single-product NT GEMM, BK=64, 8-phase counted-vmcnt.
// LDS per buffer: A[ks][256][32] + B[ks][256][32] (k-slice-major), 64 KiB.
// Phases: p0=(ks0,nh0) p1=(ks0,nh1) p2=(ks1,nh0) p3=(ks1,nh1).
// Stages at tile u (-> buffer u+1): p0:Ak0 p1:Bk0 p2:Ak1 p3:Bk1.
// Waits: vmcnt(4) at p1-end and p3-end (vmcnt(0) at last tile's p1).
// ---------------------------------------------------------------------------
__global__ __launch_bounds__(512, 2) void gemm8_nt(
    const f16* __restrict__ A_g, const f16* __restrict__ B_g,
    float* __restrict__ C, int Mrows, int Ncols, int Ktot, int Kchunk)
{
    __shared__ f16 lds[65536];

    const int tid  = threadIdx.x;
    const int lane = tid & 63;
    const int w    = tid >> 6;
    const int wr   = w >> 2;
    const int wc   = w & 3;
    const int ln15 = lane & 15;
    const int fo8  = (lane >> 4) * 8;

    const int s = xcd_swz(blockIdx.y * gridDim.x + blockIdx.x,
                          gridDim.x * gridDim.y);
    const int row0 = (s / gridDim.x) * 256;
    const int col0 = (s % gridDim.x) * 256;
    const int nkt  = Kchunk / 64;
    const size_t kbeg = (size_t)blockIdx.z * Kchunk;
    C += (size_t)blockIdx.z * Mrows * Ncols;

    f32x4 acc[8][4] = {};

    stage_unit(A_g, row0, kbeg,      Ktot, lds + 0,     tid);  // Ak0(0)
    stage_unit(B_g, col0, kbeg,      Ktot, lds + 16384, tid);  // Bk0(0)
    stage_unit(A_g, row0, kbeg + 32, Ktot, lds + 8192,  tid);  // Ak1(0)
    stage_unit(B_g, col0, kbeg + 32, Ktot, lds + 24576, tid);  // Bk1(0)
    VMCNT0();
    SBAR();

    for (int u = 0; u < nkt; ++u) {
        const int cur = (u & 1) * 32768, nxt = ((u + 1) & 1) * 32768;
        const size_t ku = kbeg + (size_t)u * 64;
        f16x8 a[8], b0, b1;

        // ---- p0: ks0, n-half 0 ----
#pragma unroll
        for (int m = 0; m < 8; ++m)
            a[m] = *(const f16x8*)&lds[cur + swz(wr * 128 + m * 16 + ln15, fo8)];
        b0 = *(const f16x8*)&lds[cur + 16384 + swz(wc * 64 +  0 + ln15, fo8)];
        b1 = *(const f16x8*)&lds[cur + 16384 + swz(wc * 64 + 16 + ln15, fo8)];
        if (u + 1 < nkt) stage_unit(A_g, row0, ku + 64, Ktot, lds + nxt + 0, tid);
        SBAR();
        __builtin_amdgcn_s_setprio(1);
#pragma unroll
        for (int m = 0; m < 8; ++m) {
            acc[m][0] = MFMA16(a[m], b0, acc[m][0]);
            acc[m][1] = MFMA16(a[m], b1, acc[m][1]);
        }
        __builtin_amdgcn_s_setprio(0);
        SBAR();

        // ---- p1: ks0, n-half 1 ----
        b0 = *(const f16x8*)&lds[cur + 16384 + swz(wc * 64 + 32 + ln15, fo8)];
        b1 = *(const f16x8*)&lds[cur + 16384 + swz(wc * 64 + 48 + ln15, fo8)];
        if (u + 1 < nkt) stage_unit(B_g, col0, ku + 64, Ktot, lds + nxt + 16384, tid);
        SBAR();
        __builtin_amdgcn_s_setprio(1);
#pragma unroll
        for (int m = 0; m < 8; ++m) {
            acc[m][2] = MFMA16(a[m], b0, acc[m][2]);
            acc[m][3] = MFMA16(a[m], b1, acc[m][3]);
        }
        __builtin_amdgcn_s_setprio(0);
        if (u == nkt - 1) { VMCNT0(); } else { VMCNT4(); }
        SBAR();

        // ---- p2: ks1, n-half 0 ----
#pragma unroll
        for (int m = 0; m < 8; ++m)
            a[m] = *(const f16x8*)&lds[cur + 8192 + swz(wr * 128 + m * 16 + ln15, fo8)];
        b0 = *(const f16x8*)&lds[cur + 24576 + swz(wc * 64 +  0 + ln15, fo8)];
        b1 = *(const f16x8*)&lds[cur + 24576 + swz(wc * 64 + 16 + ln15, fo8)];
        if (u + 1 < nkt) stage_unit(A_g, row0, ku + 96, Ktot, lds + nxt + 8192, tid);
        SBAR();
        __builtin_amdgcn_s_setprio(1);
#pragma unroll
        for (int m = 0; m < 8; ++m) {
            acc[m][0] = MFMA16(a[m], b0, acc[m][0]);
            acc[m][1] = MFMA16(a[m], b1, acc[m][1]);
        }
        __builtin_amdgcn_s_setprio(0);
        SBAR();

        // ---- p3: ks1, n-half 1 ----
        b0 = *(const f16x8*)&lds[cur + 24576 + swz(wc * 64 + 32 + ln15, fo8)];
        b1 = *(const f16x8*)&lds[cur + 24576 + swz(wc * 64 + 48 + ln15, fo8)];
        if (u + 1 < nkt) stage_unit(B_g, col0, ku + 96, Ktot, lds + nxt + 24576, tid);
        SBAR();
        __builtin_amdgcn_s_setprio(1);
#pragma unroll
        for (int m = 0; m < 8; ++m) {
            acc[m][2] = MFMA16(a[m], b0, acc[m][2]);
            acc[m][3] = MFMA16(a[m], b1, acc[m][3]);
        }
        __builtin_amdgcn_s_setprio(0);
        if (u < nkt - 1) { VMCNT4(); }
        SBAR();
    }

    const int rsub = (lane >> 4) * 4;
#pragma unroll
    for (int m = 0; m < 8; ++m)
#pragma unroll
        for (int n = 0; n < 4; ++n)
#pragma unroll
            for (int r = 0; r < 4; ++r)
                C[(size_t)(row0 + wr * 128 + m * 16 + rsub + r) * Ncols
                  + col0 + wc * 64 + n * 16 + ln15] = acc[m][n][r];
}

// ---------------------------------------------------------------------------
// split fp32 -> fp16 hi/lo (lo may be null), with scale folded in.
// ---------------------------------------------------------------------------
__global__ __launch_bounds__(256) void split_f32(
    const float* __restrict__ in, f16* __restrict__ hi, f16* __restrict__ lo,
    long n4, float scale)
{
    long i = (long)blockIdx.x * 256 + threadIdx.x;
    if (i >= n4) return;
    float4 x = ((const float4*)in)[i];
    float a = x.x * scale, b = x.y * scale, c = x.z * scale, d = x.w * scale;
    f16x4 h;
    h[0] = (f16)a; h[1] = (f16)b; h[2] = (f16)c; h[3] = (f16)d;
    ((f16x4*)hi)[i] = h;
    if (lo != nullptr) {
        f16x4 l;
        l[0] = (f16)(a - (float)h[0]);
        l[1] = (f16)(b - (float)h[1]);
        l[2] = (f16)(c - (float)h[2]);
        l[3] = (f16)(d - (float)h[3]);
        ((f16x4*)lo)[i] = l;
    }
}

// ---------------------------------------------------------------------------
// fused split fp32 -> f16 hi/lo (row-major) + hi^T, 64x64 tiles.
// lo may be null. Replaces split_f32 + transpose_h for X and Wk.
// ---------------------------------------------------------------------------
__global__ __launch_bounds__(256) void split_xt(
    const float* __restrict__ in, f16* __restrict__ hi, f16* __restrict__ lo,
    f16* __restrict__ hiT, int rows, int cols)
{
    __shared__ f16 tile[64][72];
    const int c0 = blockIdx.x * 64;
    const int r0 = blockIdx.y * 64;
    const int t = threadIdx.x;
    const int lr = t >> 3;      // 0..31
    const int lc8 = t & 7;      // 0..7
#pragma unroll
    for (int h = 0; h < 2; ++h) {
        const int r = lr + h * 32;
        const float* src = &in[(size_t)(r0 + r) * cols + c0 + lc8 * 8];
        float4 a = ((const float4*)src)[0];
        float4 b = ((const float4*)src)[1];
        float v[8] = {a.x, a.y, a.z, a.w, b.x, b.y, b.z, b.w};
        f16x8 hv, lv;
#pragma unroll
        for (int j = 0; j < 8; ++j) {
            hv[j] = (f16)v[j];
            lv[j] = (f16)(v[j] - (float)hv[j]);
        }
        *(f16x8*)&hi[(size_t)(r0 + r) * cols + c0 + lc8 * 8] = hv;
        if (lo != nullptr)
            *(f16x8*)&lo[(size_t)(r0 + r) * cols + c0 + lc8 * 8] = lv;
#pragma unroll
        for (int j = 0; j < 8; ++j) tile[r][lc8 * 8 + j] = hv[j];
    }
    __syncthreads();
#pragma unroll
    for (int h = 0; h < 2; ++h) {
        const int c = lr + h * 32;
        f16x8 v;
#pragma unroll
        for (int j = 0; j < 8; ++j) v[j] = tile[lc8 * 8 + j][c];
        *(f16x8*)&hiT[(size_t)(c0 + c) * rows + r0 + lc8 * 8] = v;
    }
}

// ---------------------------------------------------------------------------
// reduce 4 contiguous fp32 partials -> fp16 hi/lo (lo may be null), scaled
// ---------------------------------------------------------------------------
__global__ __launch_bounds__(256) void reduce4_split(
    const float* __restrict__ P, f16* __restrict__ hi, f16* __restrict__ lo,
    long n4, float scale)
{
    long i = (long)blockIdx.x * 256 + threadIdx.x;
    if (i >= n4) return;
    const float4* p = (const float4*)P;
    float4 a = p[i], b = p[i + n4], c = p[i + 2 * n4], d = p[i + 3 * n4];
    float v0 = ((a.x + b.x) + (c.x + d.x)) * scale;
    float v1 = ((a.y + b.y) + (c.y + d.y)) * scale;
    float v2 = ((a.z + b.z) + (c.z + d.z)) * scale;
    float v3 = ((a.w + b.w) + (c.w + d.w)) * scale;
    f16x4 h;
    h[0] = (f16)v0; h[1] = (f16)v1; h[2] = (f16)v2; h[3] = (f16)v3;
    ((f16x4*)hi)[i] = h;
    if (lo != nullptr) {
        f16x4 l;
        l[0] = (f16)(v0 - (float)h[0]);
        l[1] = (f16)(v1 - (float)h[1]);
        l[2] = (f16)(v2 - (float)h[2]);
        l[3] = (f16)(v3 - (float)h[3]);
        ((f16x4*)lo)[i] = l;
    }
}

// ---------------------------------------------------------------------------
// reduce 7 compact 256x256 triangle partials -> Ghi/Glo at tile (i,j)
// grid (64, NTRI8): 64x256 threads cover 256x256 float4s per tile
// ---------------------------------------------------------------------------
__global__ __launch_bounds__(256) void reduce7_tri(
    const float* __restrict__ P, f16* __restrict__ hi, f16* __restrict__ lo)
{
    const int t = blockIdx.y;
    int i = 0;
    while ((i + 1) * (i + 2) / 2 <= t) ++i;
    const int j = t - i * (i + 1) / 2;

    const int i4 = blockIdx.x * 256 + threadIdx.x;   // [0, 16384)
    const int r  = i4 >> 6;
    const int c4 = i4 & 63;
    const long zs = (long)NTRI8 * (256 * 256 / 4);   // slice stride in float4s
    const float4* q = (const float4*)P + (long)t * (256 * 256 / 4) + i4;

    float v0 = 0.f, v1 = 0.f, v2 = 0.f, v3 = 0.f;
#pragma unroll
    for (int z = 0; z < 7; ++z) {
        float4 a = q[z * zs];
        v0 += a.x; v1 += a.y; v2 += a.z; v3 += a.w;
    }
    f16x4 h;
    h[0] = (f16)v0; h[1] = (f16)v1; h[2] = (f16)v2; h[3] = (f16)v3;
    const size_t o = (size_t)(i * 256 + r) * DDIM + j * 256 + c4 * 4;
    *(f16x4*)&hi[o] = h;
    f16x4 l;
    l[0] = (f16)(v0 - (float)h[0]);
    l[1] = (f16)(v1 - (float)h[1]);
    l[2] = (f16)(v2 - (float)h[2]);
    l[3] = (f16)(v3 - (float)h[3]);
    *(f16x4*)&lo[o] = l;
}

// ---------------------------------------------------------------------------
// symmetrize: mirror strict-lower 64-tiles (a,b), a>b, transposed to (b,a)
// ---------------------------------------------------------------------------
__global__ __launch_bounds__(256) void symm_h(f16* __restrict__ Ghi, f16* __restrict__ Glo)
{
    const int a = blockIdx.y, b = blockIdx.x;
    if (a <= b) return;
    __shared__ f16 tile[64][72];
    const int t = threadIdx.x;
    const int lr = t >> 3, lc8 = t & 7;
    for (int q = 0; q < 2; ++q) {
        f16* G = q ? Glo : Ghi;
        const f16* src = G + ((size_t)a * 64) * DDIM + b * 64;
        f16* dst = G + ((size_t)b * 64) * DDIM + a * 64;
        if (q) __syncthreads();
#pragma unroll
        for (int h = 0; h < 2; ++h) {
            const int r = lr + h * 32;
            f16x8 v = *(const f16x8*)&src[(size_t)r * DDIM + lc8 * 8];
#pragma unroll
            for (int jj = 0; jj < 8; ++jj) tile[r][lc8 * 8 + jj] = v[jj];
        }
        __syncthreads();
#pragma unroll
        for (int h = 0; h < 2; ++h) {
            const int c = lr + h * 32;
            f16x8 v;
#pragma unroll
            for (int jj = 0; jj < 8; ++jj) v[jj] = tile[lc8 * 8 + jj][c];
            *(f16x8*)&dst[(size_t)c * DDIM + lc8 * 8] = v;
        }
    }
}

// ---------------------------------------------------------------------------
// row softmax over sum of 4 fp32 partials (each rows x n): -> Z fp16
// ---------------------------------------------------------------------------
__global__ __launch_bounds__(256) void softmax_rows4(
    const float* __restrict__ S, f16* __restrict__ Z, int n)
{
    const int row = blockIdx.x;
    const int t = threadIdx.x;
    const int lane = t & 63, wv = t >> 6;
    const long ps = (long)DDIM * DDIM;
    const float* s = S + (size_t)row * n + t * 8;

    float x[8] = {};
#pragma unroll
    for (int q = 0; q < 4; ++q) {
        float4 a = ((const float4*)(s + q * ps))[0];
        float4 b = ((const float4*)(s + q * ps))[1];
        x[0] += a.x; x[1] += a.y; x[2] += a.z; x[3] += a.w;
        x[4] += b.x; x[5] += b.y; x[6] += b.z; x[7] += b.w;
    }

    float m = x[0];
#pragma unroll
    for (int j = 1; j < 8; ++j) m = fmaxf(m, x[j]);
    for (int o = 32; o; o >>= 1) m = fmaxf(m, __shfl_xor(m, o, 64));

    __shared__ float rmax[4], rsum[4];
    if (lane == 0) rmax[wv] = m;
    __syncthreads();
    m = fmaxf(fmaxf(rmax[0], rmax[1]), fmaxf(rmax[2], rmax[3]));

    float e[8], sum = 0.f;
#pragma unroll
    for (int j = 0; j < 8; ++j) { e[j] = expf(x[j] - m); sum += e[j]; }
    for (int o = 32; o; o >>= 1) sum += __shfl_xor(sum, o, 64);
    if (lane == 0) rsum[wv] = sum;
    __syncthreads();
    sum = rsum[0] + rsum[1] + rsum[2] + rsum[3];
    const float rs = 1.0f / sum;

    f16x8 z;
#pragma unroll
    for (int j = 0; j < 8; ++j) z[j] = (f16)(e[j] * rs);
    *(f16x8*)&Z[(size_t)row * n + t * 8] = z;
}

// ---------------------------------------------------------------------------
extern "C" void kernel_launch(void* const* d_in, const int* in_sizes, int n_in,
                              void* d_out, int out_size, void* d_ws, size_t ws_size,
                              hipStream_t stream)
{
    const float* X  = (const float*)d_in[0];  // (D, N)
    const float* Wq = (const float*)d_in[1];  // (D, D)
    const float* Wk = (const float*)d_in[2];  // (D, D)  -> V projection (ref swap)
    const float* Wv = (const float*)d_in[3];  // (D, D)  -> K projection (ref swap)
    float* out = (float*)d_out;
    char* ws = (char*)d_ws;

    const size_t MiB = 1024 * 1024;
    const size_t NEED = 184 * MiB;
    if (ws_size < NEED) return;  // diagnostic: output stays zero -> absmax == max|ref|

    // layout (MiB offsets), lifetimes:
    f16*   Xhi   = (f16*)(ws + 0 * MiB);     // dead after G-GEMM
    f16*   Xlo   = (f16*)(ws + 32 * MiB);    // dead after G-GEMM
    f16*   XhiT  = (f16*)(ws + 64 * MiB);    // live to the end (out-GEMM B)
    float* P     = (float*)(ws + 96 * MiB);  // [96,160): G tri partials (7x9MiB) / dense 4x16MiB
    f16*   Ghi   = (f16*)(ws + 160 * MiB);   // dead after M1-GEMM
    f16*   Glo   = (f16*)(ws + 168 * MiB);   // dead after M1-GEMM
    f16*   Z     = (f16*)(ws + 176 * MiB);
    // carved from dead X region after G-GEMM:
    f16*   Wqhi  = (f16*)(ws + 0 * MiB);
    f16*   Wqlo  = (f16*)(ws + 8 * MiB);
    f16*   Wvhi  = (f16*)(ws + 16 * MiB);
    f16*   Wvlo  = (f16*)(ws + 24 * MiB);
    f16*   Wkhi  = (f16*)(ws + 32 * MiB);
    f16*   WkhiT = (f16*)(ws + 40 * MiB);
    f16*   M1hi  = (f16*)(ws + 48 * MiB);
    f16*   M1lo  = (f16*)(ws + 56 * MiB);
    f16*   ZWkhi = (f16*)(ws + 0 * MiB);     // reuses Wqhi (dead after M1-GEMM)

    const float scale = 0.022097086912079608f;  // 1/sqrt(2048)
    const long n4W = (long)DDIM * DDIM / 4;

    // split X + transpose fused (writes Xhi, Xlo, XhiT in one pass)
    split_xt<<<dim3(NDIM / 64, DDIM / 64), 256, 0, stream>>>(
        X, Xhi, Xlo, XhiT, DDIM, NDIM);

    // G = X X^T lower triangle: 36 256^2 tiles x 7 uneven K-slices = 252 blocks
    gemm8_split<true><<<dim3(NTRI8, 1, 7), 512, 0, stream>>>(
        Xhi, Xlo, Xhi, Xlo, P, DDIM, DDIM, NDIM, 0);
    reduce7_tri<<<dim3(64, NTRI8), 256, 0, stream>>>(P, Ghi, Glo);
    symm_h<<<dim3(32, 32), 256, 0, stream>>>(Ghi, Glo);

    // W splits (X regions now dead); Wk split+transpose fused
    split_f32<<<dim3(n4W / 256), 256, 0, stream>>>(Wq, Wqhi, Wqlo, n4W, 1.0f);
    split_f32<<<dim3(n4W / 256), 256, 0, stream>>>(Wv, Wvhi, Wvlo, n4W, 1.0f);
    split_xt<<<dim3(DDIM / 64, DDIM / 64), 256, 0, stream>>>(
        Wk, Wkhi, (f16*)nullptr, WkhiT, DDIM, DDIM);

    // M1 = Wq G (G symmetric -> NT works), fused split, split-K x4
    gemm8_split<false><<<dim3(8, 8, 4), 512, 0, stream>>>(
        Wqhi, Wqlo, Ghi, Glo, P, DDIM, DDIM, DDIM, DDIM / 4);
    reduce4_split<<<dim3(n4W / 256), 256, 0, stream>>>(P, M1hi, M1lo, n4W, scale);

    // S = (M1*scale) Wv^T, fused split, split-K x4 (softmax consumes partials)
    gemm8_split<false><<<dim3(8, 8, 4), 512, 0, stream>>>(
        M1hi, M1lo, Wvhi, Wvlo, P, DDIM, DDIM, DDIM, DDIM / 4);
    softmax_rows4<<<dim3(DDIM), 256, 0, stream>>>(P, Z, DDIM);

    // ZWk = Z Wk (NT with B = Wk^T), split-K x4, then collapse to fp16
    gemm8_nt<<<dim3(8, 8, 4), 512, 0, stream>>>(
        Z, WkhiT, P, DDIM, DDIM, DDIM, DDIM / 4);
    reduce4_split<<<dim3(n4W / 256), 256, 0, stream>>>(P, ZWkhi, (f16*)nullptr, n4W, 1.0f);

    // out = (Z Wk) X  (NT: A=ZWkhi (D x D), B=XhiT (N x D))
    gemm8_nt<<<dim3(32, 8, 1), 512, 0, stream>>>(
        ZWkhi, XhiT, out, DDIM, NDIM, DDIM, DDIM);
}

// Round 2
// 475.308 us; speedup vs baseline: 1.0915x; 1.0915x over previous
//
#include <hip/hip_runtime.h>
#include <math.h>

#define DDIM 2048
#define NDIM 8192
#define NTRI8 36   // lower-triangle 256x256 tiles of the 2048x2048 G (8x8 grid)

typedef _Float16 f16;
typedef _Float16 f16x8 __attribute__((ext_vector_type(8)));
typedef _Float16 f16x4 __attribute__((ext_vector_type(4)));
typedef float    f32x4 __attribute__((ext_vector_type(4)));

#define MFMA16(a, b, c) __builtin_amdgcn_mfma_f32_16x16x32_f16(a, b, c, 0, 0, 0)

__device__ __forceinline__ void gload_lds16(const f16* g, f16* l) {
    __builtin_amdgcn_global_load_lds(
        (__attribute__((address_space(1))) const void*)g,
        (__attribute__((address_space(3))) void*)l, 16, 0, 0);
}

// raw barrier (NOT __syncthreads: avoids compiler-inserted vmcnt(0) drain)
#define SBAR() do { __builtin_amdgcn_sched_barrier(0); \
                    __builtin_amdgcn_s_barrier();      \
                    __builtin_amdgcn_sched_barrier(0); } while (0)
#define VMCNT0() asm volatile("s_waitcnt vmcnt(0)" ::: "memory")
#define VMCNT2() asm volatile("s_waitcnt vmcnt(2)" ::: "memory")
#define VMCNT4() asm volatile("s_waitcnt vmcnt(4)" ::: "memory")
#define VMCNT8() asm volatile("s_waitcnt vmcnt(8)" ::: "memory")

// bijective XCD-chunk swizzle (m204): n may be non-multiple of 8
__device__ __forceinline__ int xcd_swz(int lin, int n) {
    const int xcd = lin & 7, pos = lin >> 3;
    const int q = n >> 3, r = n & 7;
    return (xcd < r ? xcd * (q + 1) : r * (q + 1) + (xcd - r) * q) + pos;
}

// ---------------------------------------------------------------------------
// T2 bank-conflict swizzle for the [256 rows][32 f16] LDS unit (64 B rows).
// 16-B k-slot j of row R lives at slot j ^ ((R>>1)&3). Applied BOTH on the
// global source (stage) and on the read -> involution, rule #21 satisfied.
// ---------------------------------------------------------------------------
__device__ __forceinline__ int swz(int R, int fo8) {
    return R * 32 + (fo8 ^ (((R >> 1) & 3) << 3));
}

// stage one 16 KiB unit (256 rows x 32 k-elems, f16) global -> LDS.
// LDS dest linear (gload_lds requirement); source k-slot pre-swizzled.
__device__ __forceinline__ void stage_unit(
    const f16* __restrict__ g, int grow0, size_t kelem, int Ktot,
    f16* ldsbase, int tid)
{
#pragma unroll
    for (int i = 0; i < 2; ++i) {
        const int c = tid + i * 512;
        const int row  = c >> 2;
        const int slot = (c & 3) ^ ((c >> 3) & 3);   // (c&3) ^ ((row>>1)&3)
        gload_lds16(g + (size_t)(grow0 + row) * Ktot + kelem + slot * 8,
                    ldsbase + c * 8);
    }
}

// ---------------------------------------------------------------------------
// K2: 256x256 FUSED split-fp16 NT GEMM, 8-phase counted-vmcnt schedule.
//   C_z += Ah Bh^T + Al Bh^T + Ah Bl^T   over the block's K-chunk.
// BK=32; units {Ah,Al,Bh,Bl} of 16 KiB; LDS = 2 buf x 64 KiB = 128 KiB.
// 8 waves (2M x 4N), per-wave 128x64 output, acc 8x4 fragments.
// Phases/K-tile: P0=HH(nh0) P1=HH(nh1) P2=LH P3=HL(ah LIVE from P0 --
//   round-0 re-read of Ah dropped: 24 ds_reads/tile vs 32).
// Stages: P0:Bh(u+1) P1:Ah(u+1) P2:Bl(u+1) P3:Al(u+2, same buffer).
// Waits:  P2-end vmcnt(8), P3-end vmcnt(4); tails: u==nkt-2 -> vmcnt(2)@P3,
//         u==nkt-1 -> vmcnt(0)@P2.   [round-1 3-phase regressed dense 2x:
//         1-tile-ahead staging + merged read phase broke the pipeline]
// ---------------------------------------------------------------------------
template <bool TRI>
__global__ __launch_bounds__(512, 2) void gemm8_split(
    const f16* __restrict__ Ah_g, const f16* __restrict__ Al_g,
    const f16* __restrict__ Bh_g, const f16* __restrict__ Bl_g,
    float* __restrict__ C, int Mrows, int Ncols, int Ktot, int Kchunk)
{
    __shared__ f16 lds[65536];   // 128 KiB

    const int tid  = threadIdx.x;
    const int lane = tid & 63;
    const int w    = tid >> 6;
    const int wr   = w >> 2;          // 0..1
    const int wc   = w & 3;           // 0..3
    const int ln15 = lane & 15;
    const int fo8  = (lane >> 4) * 8;

    int row0, col0, nkt;
    size_t kbeg;
    if constexpr (TRI) {
        const int t = xcd_swz(blockIdx.x, NTRI8);
        int i = 0;
        while ((i + 1) * (i + 2) / 2 <= t) ++i;
        const int j = t - i * (i + 1) / 2;
        row0 = i * 256; col0 = j * 256;
        const int z = blockIdx.z;                       // 0..6, uneven chunks
        const int kb_u = z * 37 - (z > 4 ? z - 4 : 0);  // 37,37,37,37,36,36,36
        nkt = (z < 4) ? 37 : 36;
        kbeg = (size_t)kb_u * 32;
        C += ((size_t)z * NTRI8 + t) * (256 * 256);     // compact partial
    } else {
        const int s = xcd_swz(blockIdx.y * gridDim.x + blockIdx.x,
                              gridDim.x * gridDim.y);
        row0 = (s / gridDim.x) * 256;
        col0 = (s % gridDim.x) * 256;
        nkt  = Kchunk / 32;
        kbeg = (size_t)blockIdx.z * Kchunk;
        C += (size_t)blockIdx.z * Mrows * Ncols;
    }

    f32x4 acc[8][4] = {};

    // prologue: tile0's 4 units + Al(1); drain; barrier
    stage_unit(Ah_g, row0, kbeg, Ktot, lds + 0,     tid);
    stage_unit(Al_g, row0, kbeg, Ktot, lds + 8192,  tid);
    stage_unit(Bh_g, col0, kbeg, Ktot, lds + 16384, tid);
    stage_unit(Bl_g, col0, kbeg, Ktot, lds + 24576, tid);
    if (nkt > 1)
        stage_unit(Al_g, row0, kbeg + 32, Ktot, lds + 32768 + 8192, tid);
    VMCNT0();
    SBAR();

    for (int u = 0; u < nkt; ++u) {
        const int cur = (u & 1) * 32768, nxt = ((u + 1) & 1) * 32768;
        const size_t ku = kbeg + (size_t)u * 32;
        f16x8 ah[8], bh[4];

        // ---- P0: HH, n-half 0 ----
#pragma unroll
        for (int m = 0; m < 8; ++m)
            ah[m] = *(const f16x8*)&lds[cur + swz(wr * 128 + m * 16 + ln15, fo8)];
        bh[0] = *(const f16x8*)&lds[cur + 16384 + swz(wc * 64 +  0 + ln15, fo8)];
        bh[1] = *(const f16x8*)&lds[cur + 16384 + swz(wc * 64 + 16 + ln15, fo8)];
        if (u + 1 < nkt) stage_unit(Bh_g, col0, ku + 32, Ktot, lds + nxt + 16384, tid);
        SBAR();
        __builtin_amdgcn_s_setprio(1);
#pragma unroll
        for (int m = 0; m < 8; ++m) {
            acc[m][0] = MFMA16(ah[m], bh[0], acc[m][0]);
            acc[m][1] = MFMA16(ah[m], bh[1], acc[m][1]);
        }
        __builtin_amdgcn_s_setprio(0);
        SBAR();

        // ---- P1: HH, n-half 1 ----
        bh[2] = *(const f16x8*)&lds[cur + 16384 + swz(wc * 64 + 32 + ln15, fo8)];
        bh[3] = *(const f16x8*)&lds[cur + 16384 + swz(wc * 64 + 48 + ln15, fo8)];
        if (u + 1 < nkt) stage_unit(Ah_g, row0, ku + 32, Ktot, lds + nxt + 0, tid);
        SBAR();
        __builtin_amdgcn_s_setprio(1);
#pragma unroll
        for (int m = 0; m < 8; ++m) {
            acc[m][2] = MFMA16(ah[m], bh[2], acc[m][2]);
            acc[m][3] = MFMA16(ah[m], bh[3], acc[m][3]);
        }
        __builtin_amdgcn_s_setprio(0);
        SBAR();

        // ---- P2: LH, all n ----
        {
            f16x8 al[8];
#pragma unroll
            for (int m = 0; m < 8; ++m)
                al[m] = *(const f16x8*)&lds[cur + 8192 + swz(wr * 128 + m * 16 + ln15, fo8)];
            if (u + 1 < nkt) stage_unit(Bl_g, col0, ku + 32, Ktot, lds + nxt + 24576, tid);
            SBAR();
            __builtin_amdgcn_s_setprio(1);
#pragma unroll
            for (int m = 0; m < 8; ++m)
#pragma unroll
                for (int n = 0; n < 4; ++n)
                    acc[m][n] = MFMA16(al[m], bh[n], acc[m][n]);
            __builtin_amdgcn_s_setprio(0);
        }
        if (u == nkt - 1) { VMCNT0(); } else { VMCNT8(); }
        SBAR();

        // ---- P3: HL, all n (ah LIVE from P0; no re-read) ----
        {
            f16x8 bl[4];
#pragma unroll
            for (int n = 0; n < 4; ++n)
                bl[n] = *(const f16x8*)&lds[cur + 24576 + swz(wc * 64 + n * 16 + ln15, fo8)];
            if (u + 2 < nkt) stage_unit(Al_g, row0, ku + 64, Ktot, lds + cur + 8192, tid);
            SBAR();
            __builtin_amdgcn_s_setprio(1);
#pragma unroll
            for (int m = 0; m < 8; ++m)
#pragma unroll
                for (int n = 0; n < 4; ++n)
                    acc[m][n] = MFMA16(ah[m], bl[n], acc[m][n]);
            __builtin_amdgcn_s_setprio(0);
        }
        if (u < nkt - 2) { VMCNT4(); }
        else if (u == nkt - 2) { VMCNT2(); }
        SBAR();
    }

    // epilogue: C/D layout col=lane&15, row=(lane>>4)*4+reg [m89-verified]
    const int rsub = (lane >> 4) * 4;
#pragma unroll
    for (int m = 0; m < 8; ++m)
#pragma unroll
        for (int n = 0; n < 4; ++n)
#pragma unroll
            for (int r = 0; r < 4; ++r) {
                const int cr = wr * 128 + m * 16 + rsub + r;
                const int cc = wc * 64 + n * 16 + ln15;
                if constexpr (TRI)
                    C[(size_t)cr * 256 + cc] = acc[m][n][r];
                else
                    C[(size_t)(row0 + cr) * Ncols + col0 + cc] = acc[m][n][r];
            }
}

// ---------------------------------------------------------------------------
// K1: 256x256 single-product NT GEMM, BK=64, 8-phase counted-vmcnt.
// LDS per buffer: A[ks][256][32] + B[ks][256][32] (k-slice-major), 64 KiB.
// Phases: p0=(ks0,nh0) p1=(ks0,nh1) p2=(ks1,nh0) p3=(ks1,nh1).
// Stages at tile u (-> buffer u+1): p0:Ak0 p1:Bk0 p2:Ak1 p3:Bk1.
// Waits: vmcnt(4) at p1-end and p3-end (vmcnt(0) at last tile's p1).
// ---------------------------------------------------------------------------
__global__ __launch_bounds__(512, 2) void gemm8_nt(
    const f16* __restrict__ A_g, const f16* __restrict__ B_g,
    float* __restrict__ C, int Mrows, int Ncols, int Ktot, int Kchunk)
{
    __shared__ f16 lds[65536];

    const int tid  = threadIdx.x;
    const int lane = tid & 63;
    const int w    = tid >> 6;
    const int wr   = w >> 2;
    const int wc   = w & 3;
    const int ln15 = lane & 15;
    const int fo8  = (lane >> 4) * 8;

    const int s = xcd_swz(blockIdx.y * gridDim.x + blockIdx.x,
                          gridDim.x * gridDim.y);
    const int row0 = (s / gridDim.x) * 256;
    const int col0 = (s % gridDim.x) * 256;
    const int nkt  = Kchunk / 64;
    const size_t kbeg = (size_t)blockIdx.z * Kchunk;
    C += (size_t)blockIdx.z * Mrows * Ncols;

    f32x4 acc[8][4] = {};

    stage_unit(A_g, row0, kbeg,      Ktot, lds + 0,     tid);  // Ak0(0)
    stage_unit(B_g, col0, kbeg,      Ktot, lds + 16384, tid);  // Bk0(0)
    stage_unit(A_g, row0, kbeg + 32, Ktot, lds + 8192,  tid);  // Ak1(0)
    stage_unit(B_g, col0, kbeg + 32, Ktot, lds + 24576, tid);  // Bk1(0)
    VMCNT0();
    SBAR();

    for (int u = 0; u < nkt; ++u) {
        const int cur = (u & 1) * 32768, nxt = ((u + 1) & 1) * 32768;
        const size_t ku = kbeg + (size_t)u * 64;
        f16x8 a[8], b0, b1;

        // ---- p0: ks0, n-half 0 ----
#pragma unroll
        for (int m = 0; m < 8; ++m)
            a[m] = *(const f16x8*)&lds[cur + swz(wr * 128 + m * 16 + ln15, fo8)];
        b0 = *(const f16x8*)&lds[cur + 16384 + swz(wc * 64 +  0 + ln15, fo8)];
        b1 = *(const f16x8*)&lds[cur + 16384 + swz(wc * 64 + 16 + ln15, fo8)];
        if (u + 1 < nkt) stage_unit(A_g, row0, ku + 64, Ktot, lds + nxt + 0, tid);
        SBAR();
        __builtin_amdgcn_s_setprio(1);
#pragma unroll
        for (int m = 0; m < 8; ++m) {
            acc[m][0] = MFMA16(a[m], b0, acc[m][0]);
            acc[m][1] = MFMA16(a[m], b1, acc[m][1]);
        }
        __builtin_amdgcn_s_setprio(0);
        SBAR();

        // ---- p1: ks0, n-half 1 ----
        b0 = *(const f16x8*)&lds[cur + 16384 + swz(wc * 64 + 32 + ln15, fo8)];
        b1 = *(const f16x8*)&lds[cur + 16384 + swz(wc * 64 + 48 + ln15, fo8)];
        if (u + 1 < nkt) stage_unit(B_g, col0, ku + 64, Ktot, lds + nxt + 16384, tid);
        SBAR();
        __builtin_amdgcn_s_setprio(1);
#pragma unroll
        for (int m = 0; m < 8; ++m) {
            acc[m][2] = MFMA16(a[m], b0, acc[m][2]);
            acc[m][3] = MFMA16(a[m], b1, acc[m][3]);
        }
        __builtin_amdgcn_s_setprio(0);
        if (u == nkt - 1) { VMCNT0(); } else { VMCNT4(); }
        SBAR();

        // ---- p2: ks1, n-half 0 ----
#pragma unroll
        for (int m = 0; m < 8; ++m)
            a[m] = *(const f16x8*)&lds[cur + 8192 + swz(wr * 128 + m * 16 + ln15, fo8)];
        b0 = *(const f16x8*)&lds[cur + 24576 + swz(wc * 64 +  0 + ln15, fo8)];
        b1 = *(const f16x8*)&lds[cur + 24576 + swz(wc * 64 + 16 + ln15, fo8)];
        if (u + 1 < nkt) stage_unit(A_g, row0, ku + 96, Ktot, lds + nxt + 8192, tid);
        SBAR();
        __builtin_amdgcn_s_setprio(1);
#pragma unroll
        for (int m = 0; m < 8; ++m) {
            acc[m][0] = MFMA16(a[m], b0, acc[m][0]);
            acc[m][1] = MFMA16(a[m], b1, acc[m][1]);
        }
        __builtin_amdgcn_s_setprio(0);
        SBAR();

        // ---- p3: ks1, n-half 1 ----
        b0 = *(const f16x8*)&lds[cur + 24576 + swz(wc * 64 + 32 + ln15, fo8)];
        b1 = *(const f16x8*)&lds[cur + 24576 + swz(wc * 64 + 48 + ln15, fo8)];
        if (u + 1 < nkt) stage_unit(B_g, col0, ku + 96, Ktot, lds + nxt + 24576, tid);
        SBAR();
        __builtin_amdgcn_s_setprio(1);
#pragma unroll
        for (int m = 0; m < 8; ++m) {
            acc[m][2] = MFMA16(a[m], b0, acc[m][2]);
            acc[m][3] = MFMA16(a[m], b1, acc[m][3]);
        }
        __builtin_amdgcn_s_setprio(0);
        if (u < nkt - 1) { VMCNT4(); }
        SBAR();
    }

    const int rsub = (lane >> 4) * 4;
#pragma unroll
    for (int m = 0; m < 8; ++m)
#pragma unroll
        for (int n = 0; n < 4; ++n)
#pragma unroll
            for (int r = 0; r < 4; ++r)
                C[(size_t)(row0 + wr * 128 + m * 16 + rsub + r) * Ncols
                  + col0 + wc * 64 + n * 16 + ln15] = acc[m][n][r];
}

// ---------------------------------------------------------------------------
// split fp32 -> fp16 hi/lo (lo may be null), with scale folded in.
// ---------------------------------------------------------------------------
__global__ __launch_bounds__(256) void split_f32(
    const float* __restrict__ in, f16* __restrict__ hi, f16* __restrict__ lo,
    long n4, float scale)
{
    long i = (long)blockIdx.x * 256 + threadIdx.x;
    if (i >= n4) return;
    float4 x = ((const float4*)in)[i];
    float a = x.x * scale, b = x.y * scale, c = x.z * scale, d = x.w * scale;
    f16x4 h;
    h[0] = (f16)a; h[1] = (f16)b; h[2] = (f16)c; h[3] = (f16)d;
    ((f16x4*)hi)[i] = h;
    if (lo != nullptr) {
        f16x4 l;
        l[0] = (f16)(a - (float)h[0]);
        l[1] = (f16)(b - (float)h[1]);
        l[2] = (f16)(c - (float)h[2]);
        l[3] = (f16)(d - (float)h[3]);
        ((f16x4*)lo)[i] = l;
    }
}

// ---------------------------------------------------------------------------
// fused split fp32 -> f16 hi/lo (row-major) + hi^T, 64x64 tiles.
// lo may be null. Replaces split_f32 + transpose_h for X and Wk.
// ---------------------------------------------------------------------------
__global__ __launch_bounds__(256) void split_xt(
    const float* __restrict__ in, f16* __restrict__ hi, f16* __restrict__ lo,
    f16* __restrict__ hiT, int rows, int cols)
{
    __shared__ f16 tile[64][72];
    const int c0 = blockIdx.x * 64;
    const int r0 = blockIdx.y * 64;
    const int t = threadIdx.x;
    const int lr = t >> 3;      // 0..31
    const int lc8 = t & 7;      // 0..7
#pragma unroll
    for (int h = 0; h < 2; ++h) {
        const int r = lr + h * 32;
        const float* src = &in[(size_t)(r0 + r) * cols + c0 + lc8 * 8];
        float4 a = ((const float4*)src)[0];
        float4 b = ((const float4*)src)[1];
        float v[8] = {a.x, a.y, a.z, a.w, b.x, b.y, b.z, b.w};
        f16x8 hv, lv;
#pragma unroll
        for (int j = 0; j < 8; ++j) {
            hv[j] = (f16)v[j];
            lv[j] = (f16)(v[j] - (float)hv[j]);
        }
        *(f16x8*)&hi[(size_t)(r0 + r) * cols + c0 + lc8 * 8] = hv;
        if (lo != nullptr)
            *(f16x8*)&lo[(size_t)(r0 + r) * cols + c0 + lc8 * 8] = lv;
#pragma unroll
        for (int j = 0; j < 8; ++j) tile[r][lc8 * 8 + j] = hv[j];
    }
    __syncthreads();
#pragma unroll
    for (int h = 0; h < 2; ++h) {
        const int c = lr + h * 32;
        f16x8 v;
#pragma unroll
        for (int j = 0; j < 8; ++j) v[j] = tile[lc8 * 8 + j][c];
        *(f16x8*)&hiT[(size_t)(c0 + c) * rows + r0 + lc8 * 8] = v;
    }
}

// ---------------------------------------------------------------------------
// reduce 4 contiguous fp32 partials -> fp16 hi/lo (lo may be null), scaled
// ---------------------------------------------------------------------------
__global__ __launch_bounds__(256) void reduce4_split(
    const float* __restrict__ P, f16* __restrict__ hi, f16* __restrict__ lo,
    long n4, float scale)
{
    long i = (long)blockIdx.x * 256 + threadIdx.x;
    if (i >= n4) return;
    const float4* p = (const float4*)P;
    float4 a = p[i], b = p[i + n4], c = p[i + 2 * n4], d = p[i + 3 * n4];
    float v0 = ((a.x + b.x) + (c.x + d.x)) * scale;
    float v1 = ((a.y + b.y) + (c.y + d.y)) * scale;
    float v2 = ((a.z + b.z) + (c.z + d.z)) * scale;
    float v3 = ((a.w + b.w) + (c.w + d.w)) * scale;
    f16x4 h;
    h[0] = (f16)v0; h[1] = (f16)v1; h[2] = (f16)v2; h[3] = (f16)v3;
    ((f16x4*)hi)[i] = h;
    if (lo != nullptr) {
        f16x4 l;
        l[0] = (f16)(v0 - (float)h[0]);
        l[1] = (f16)(v1 - (float)h[1]);
        l[2] = (f16)(v2 - (float)h[2]);
        l[3] = (f16)(v3 - (float)h[3]);
        ((f16x4*)lo)[i] = l;
    }
}

// ---------------------------------------------------------------------------
// reduce 7 compact 256x256 triangle partials -> Ghi/Glo at tile (i,j)
// grid (64, NTRI8): 64x256 threads cover 256x256 float4s per tile
// ---------------------------------------------------------------------------
__global__ __launch_bounds__(256) void reduce7_tri(
    const float* __restrict__ P, f16* __restrict__ hi, f16* __restrict__ lo)
{
    const int t = blockIdx.y;
    int i = 0;
    while ((i + 1) * (i + 2) / 2 <= t) ++i;
    const int j = t - i * (i + 1) / 2;

    const int i4 = blockIdx.x * 256 + threadIdx.x;   // [0, 16384)
    const int r  = i4 >> 6;
    const int c4 = i4 & 63;
    const long zs = (long)NTRI8 * (256 * 256 / 4);   // slice stride in float4s
    const float4* q = (const float4*)P + (long)t * (256 * 256 / 4) + i4;

    float v0 = 0.f, v1 = 0.f, v2 = 0.f, v3 = 0.f;
#pragma unroll
    for (int z = 0; z < 7; ++z) {
        float4 a = q[z * zs];
        v0 += a.x; v1 += a.y; v2 += a.z; v3 += a.w;
    }
    f16x4 h;
    h[0] = (f16)v0; h[1] = (f16)v1; h[2] = (f16)v2; h[3] = (f16)v3;
    const size_t o = (size_t)(i * 256 + r) * DDIM + j * 256 + c4 * 4;
    *(f16x4*)&hi[o] = h;
    f16x4 l;
    l[0] = (f16)(v0 - (float)h[0]);
    l[1] = (f16)(v1 - (float)h[1]);
    l[2] = (f16)(v2 - (float)h[2]);
    l[3] = (f16)(v3 - (float)h[3]);
    *(f16x4*)&lo[o] = l;
}

// ---------------------------------------------------------------------------
// symmetrize: mirror strict-lower 64-tiles (a,b), a>b, transposed to (b,a)
// ---------------------------------------------------------------------------
__global__ __launch_bounds__(256) void symm_h(f16* __restrict__ Ghi, f16* __restrict__ Glo)
{
    const int a = blockIdx.y, b = blockIdx.x;
    if (a <= b) return;
    __shared__ f16 tile[64][72];
    const int t = threadIdx.x;
    const int lr = t >> 3, lc8 = t & 7;
    for (int q = 0; q < 2; ++q) {
        f16* G = q ? Glo : Ghi;
        const f16* src = G + ((size_t)a * 64) * DDIM + b * 64;
        f16* dst = G + ((size_t)b * 64) * DDIM + a * 64;
        if (q) __syncthreads();
#pragma unroll
        for (int h = 0; h < 2; ++h) {
            const int r = lr + h * 32;
            f16x8 v = *(const f16x8*)&src[(size_t)r * DDIM + lc8 * 8];
#pragma unroll
            for (int jj = 0; jj < 8; ++jj) tile[r][lc8 * 8 + jj] = v[jj];
        }
        __syncthreads();
#pragma unroll
        for (int h = 0; h < 2; ++h) {
            const int c = lr + h * 32;
            f16x8 v;
#pragma unroll
            for (int jj = 0; jj < 8; ++jj) v[jj] = tile[lc8 * 8 + jj][c];
            *(f16x8*)&dst[(size_t)c * DDIM + lc8 * 8] = v;
        }
    }
}

// ---------------------------------------------------------------------------
// row softmax over sum of 4 fp32 partials (each rows x n): -> Z fp16
// ---------------------------------------------------------------------------
__global__ __launch_bounds__(256) void softmax_rows4(
    const float* __restrict__ S, f16* __restrict__ Z, int n)
{
    const int row = blockIdx.x;
    const int t = threadIdx.x;
    const int lane = t & 63, wv = t >> 6;
    const long ps = (long)DDIM * DDIM;
    const float* s = S + (size_t)row * n + t * 8;

    float x[8] = {};
#pragma unroll
    for (int q = 0; q < 4; ++q) {
        float4 a = ((const float4*)(s + q * ps))[0];
        float4 b = ((const float4*)(s + q * ps))[1];
        x[0] += a.x; x[1] += a.y; x[2] += a.z; x[3] += a.w;
        x[4] += b.x; x[5] += b.y; x[6] += b.z; x[7] += b.w;
    }

    float m = x[0];
#pragma unroll
    for (int j = 1; j < 8; ++j) m = fmaxf(m, x[j]);
    for (int o = 32; o; o >>= 1) m = fmaxf(m, __shfl_xor(m, o, 64));

    __shared__ float rmax[4], rsum[4];
    if (lane == 0) rmax[wv] = m;
    __syncthreads();
    m = fmaxf(fmaxf(rmax[0], rmax[1]), fmaxf(rmax[2], rmax[3]));

    float e[8], sum = 0.f;
#pragma unroll
    for (int j = 0; j < 8; ++j) { e[j] = expf(x[j] - m); sum += e[j]; }
    for (int o = 32; o; o >>= 1) sum += __shfl_xor(sum, o, 64);
    if (lane == 0) rsum[wv] = sum;
    __syncthreads();
    sum = rsum[0] + rsum[1] + rsum[2] + rsum[3];
    const float rs = 1.0f / sum;

    f16x8 z;
#pragma unroll
    for (int j = 0; j < 8; ++j) z[j] = (f16)(e[j] * rs);
    *(f16x8*)&Z[(size_t)row * n + t * 8] = z;
}

// ---------------------------------------------------------------------------
extern "C" void kernel_launch(void* const* d_in, const int* in_sizes, int n_in,
                              void* d_out, int out_size, void* d_ws, size_t ws_size,
                              hipStream_t stream)
{
    const float* X  = (const float*)d_in[0];  // (D, N)
    const float* Wq = (const float*)d_in[1];  // (D, D)
    const float* Wk = (const float*)d_in[2];  // (D, D)  -> V projection (ref swap)
    const float* Wv = (const float*)d_in[3];  // (D, D)  -> K projection (ref swap)
    float* out = (float*)d_out;
    char* ws = (char*)d_ws;

    const size_t MiB = 1024 * 1024;
    const size_t NEED = 184 * MiB;
    if (ws_size < NEED) return;  // diagnostic: output stays zero -> absmax == max|ref|

    // layout (MiB offsets), lifetimes:
    f16*   Xhi   = (f16*)(ws + 0 * MiB);     // dead after G-GEMM
    f16*   Xlo   = (f16*)(ws + 32 * MiB);    // dead after G-GEMM
    f16*   XhiT  = (f16*)(ws + 64 * MiB);    // live to the end (out-GEMM B)
    float* P     = (float*)(ws + 96 * MiB);  // [96,160): G tri partials (7x9MiB) / dense 4x16MiB
    f16*   Ghi   = (f16*)(ws + 160 * MiB);   // dead after M1-GEMM
    f16*   Glo   = (f16*)(ws + 168 * MiB);   // dead after M1-GEMM
    f16*   Z     = (f16*)(ws + 176 * MiB);
    // carved from dead X region after G-GEMM:
    f16*   Wqhi  = (f16*)(ws + 0 * MiB);
    f16*   Wqlo  = (f16*)(ws + 8 * MiB);
    f16*   Wvhi  = (f16*)(ws + 16 * MiB);
    f16*   Wvlo  = (f16*)(ws + 24 * MiB);
    f16*   Wkhi  = (f16*)(ws + 32 * MiB);
    f16*   WkhiT = (f16*)(ws + 40 * MiB);
    f16*   M1hi  = (f16*)(ws + 48 * MiB);
    f16*   M1lo  = (f16*)(ws + 56 * MiB);
    f16*   ZWkhi = (f16*)(ws + 0 * MiB);     // reuses Wqhi (dead after M1-GEMM)

    const float scale = 0.022097086912079608f;  // 1/sqrt(2048)
    const long n4W = (long)DDIM * DDIM / 4;

    // split X + transpose fused (writes Xhi, Xlo, XhiT in one pass)
    split_xt<<<dim3(NDIM / 64, DDIM / 64), 256, 0, stream>>>(
        X, Xhi, Xlo, XhiT, DDIM, NDIM);

    // G = X X^T lower triangle: 36 256^2 tiles x 7 uneven K-slices = 252 blocks
    gemm8_split<true><<<dim3(NTRI8, 1, 7), 512, 0, stream>>>(
        Xhi, Xlo, Xhi, Xlo, P, DDIM, DDIM, NDIM, 0);
    reduce7_tri<<<dim3(64, NTRI8), 256, 0, stream>>>(P, Ghi, Glo);
    symm_h<<<dim3(32, 32), 256, 0, stream>>>(Ghi, Glo);

    // W splits (X regions now dead); Wk split+transpose fused
    split_f32<<<dim3(n4W / 256), 256, 0, stream>>>(Wq, Wqhi, Wqlo, n4W, 1.0f);
    split_f32<<<dim3(n4W / 256), 256, 0, stream>>>(Wv, Wvhi, Wvlo, n4W, 1.0f);
    split_xt<<<dim3(DDIM / 64, DDIM / 64), 256, 0, stream>>>(
        Wk, Wkhi, (f16*)nullptr, WkhiT, DDIM, DDIM);

    // M1 = Wq G (G symmetric -> NT works), fused split, split-K x4
    gemm8_split<false><<<dim3(8, 8, 4), 512, 0, stream>>>(
        Wqhi, Wqlo, Ghi, Glo, P, DDIM, DDIM, DDIM, DDIM / 4);
    reduce4_split<<<dim3(n4W / 256), 256, 0, stream>>>(P, M1hi, M1lo, n4W, scale);

    // S = (M1*scale) Wv^T, fused split, split-K x4 (softmax consumes partials)
    gemm8_split<false><<<dim3(8, 8, 4), 512, 0, stream>>>(
        M1hi, M1lo, Wvhi, Wvlo, P, DDIM, DDIM, DDIM, DDIM / 4);
    softmax_rows4<<<dim3(DDIM), 256, 0, stream>>>(P, Z, DDIM);

    // ZWk = Z Wk (NT with B = Wk^T), split-K x4, then collapse to fp16
    gemm8_nt<<<dim3(8, 8, 4), 512, 0, stream>>>(
        Z, WkhiT, P, DDIM, DDIM, DDIM, DDIM / 4);
    reduce4_split<<<dim3(n4W / 256), 256, 0, stream>>>(P, ZWkhi, (f16*)nullptr, n4W, 1.0f);

    // out = (Z Wk) X  (NT: A=ZWkhi (D x D), B=XhiT (N x D))
    gemm8_nt<<<dim3(32, 8, 1), 512, 0, stream>>>(
        ZWkhi, XhiT, out, DDIM, NDIM, DDIM, DDIM);
}

// Round 3
// 419.333 us; speedup vs baseline: 1.2372x; 1.1335x over previous
//
#include <hip/hip_runtime.h>
#include <math.h>

#define DDIM 2048
#define NDIM 8192
#define NTRI8 36   // lower-triangle 256x256 tiles of the 2048x2048 G (8x8 grid)

typedef _Float16 f16;
typedef _Float16 f16x8 __attribute__((ext_vector_type(8)));
typedef _Float16 f16x4 __attribute__((ext_vector_type(4)));
typedef float    f32x4 __attribute__((ext_vector_type(4)));

#define MFMA16(a, b, c) __builtin_amdgcn_mfma_f32_16x16x32_f16(a, b, c, 0, 0, 0)

__device__ __forceinline__ void gload_lds16(const f16* g, f16* l) {
    __builtin_amdgcn_global_load_lds(
        (__attribute__((address_space(1))) const void*)g,
        (__attribute__((address_space(3))) void*)l, 16, 0, 0);
}

// raw barrier (NOT __syncthreads: avoids compiler-inserted vmcnt(0) drain)
#define SBAR() do { __builtin_amdgcn_sched_barrier(0); \
                    __builtin_amdgcn_s_barrier();      \
                    __builtin_amdgcn_sched_barrier(0); } while (0)
#define VMCNT0() asm volatile("s_waitcnt vmcnt(0)" ::: "memory")
#define VMCNT2() asm volatile("s_waitcnt vmcnt(2)" ::: "memory")
#define VMCNT4() asm volatile("s_waitcnt vmcnt(4)" ::: "memory")
#define VMCNT8() asm volatile("s_waitcnt vmcnt(8)" ::: "memory")

// bijective XCD-chunk swizzle (m204): n may be non-multiple of 8
__device__ __forceinline__ int xcd_swz(int lin, int n) {
    const int xcd = lin & 7, pos = lin >> 3;
    const int q = n >> 3, r = n & 7;
    return (xcd < r ? xcd * (q + 1) : r * (q + 1) + (xcd - r) * q) + pos;
}

// ---------------------------------------------------------------------------
// T2 bank-conflict swizzle for the [256 rows][32 f16] LDS unit (64 B rows).
// 16-B k-slot j of row R lives at slot j ^ ((R>>1)&3). Applied BOTH on the
// global source (stage) and on the read -> involution, rule #21 satisfied.
// ---------------------------------------------------------------------------
__device__ __forceinline__ int swz(int R, int fo8) {
    return R * 32 + (fo8 ^ (((R >> 1) & 3) << 3));
}

// stage one 16 KiB unit (256 rows x 32 k-elems, f16) global -> LDS.
// LDS dest linear (gload_lds requirement); source k-slot pre-swizzled.
__device__ __forceinline__ void stage_unit(
    const f16* __restrict__ g, int grow0, size_t kelem, int Ktot,
    f16* ldsbase, int tid)
{
#pragma unroll
    for (int i = 0; i < 2; ++i) {
        const int c = tid + i * 512;
        const int row  = c >> 2;
        const int slot = (c & 3) ^ ((c >> 3) & 3);   // (c&3) ^ ((row>>1)&3)
        gload_lds16(g + (size_t)(grow0 + row) * Ktot + kelem + slot * 8,
                    ldsbase + c * 8);
    }
}

// ---------------------------------------------------------------------------
// K2: 256x256 FUSED split-fp16 NT GEMM, 8-phase counted-vmcnt schedule.
//   C_z += Ah Bh^T + Al Bh^T + Ah Bl^T   over the block's K-chunk.
// BK=32; units {Ah,Al,Bh,Bl} of 16 KiB; LDS = 2 buf x 64 KiB = 128 KiB.
// 8 waves (2M x 4N), per-wave 128x64 output, acc 8x4 fragments.
// Phases/K-tile: P0=HH(nh0) P1=HH(nh1) P2=LH P3=HL.
// P3 A-operand is PER-INSTANTIATION (R2 A/B result):
//   TRI:  ah kept LIVE from P0 (24 ds_reads/tile) -- measured faster (102 vs 105)
//   dense: a2 re-read from LDS (32 ds_reads/tile) -- R0 schedule; R2's ah-live
//          correlated with dense ~87us vs R0 ~60us (attribution test this round)
// Stages: P0:Bh(u+1) P1:Ah(u+1) P2:Bl(u+1) P3:Al(u+2, same buffer).
// Waits:  P2-end vmcnt(8), P3-end vmcnt(4); tails: u==nkt-2 -> vmcnt(2)@P3,
//         u==nkt-1 -> vmcnt(0)@P2.
// ---------------------------------------------------------------------------
template <bool TRI>
__global__ __launch_bounds__(512, 2) void gemm8_split(
    const f16* __restrict__ Ah_g, const f16* __restrict__ Al_g,
    const f16* __restrict__ Bh_g, const f16* __restrict__ Bl_g,
    float* __restrict__ C, int Mrows, int Ncols, int Ktot, int Kchunk)
{
    __shared__ f16 lds[65536];   // 128 KiB

    const int tid  = threadIdx.x;
    const int lane = tid & 63;
    const int w    = tid >> 6;
    const int wr   = w >> 2;          // 0..1
    const int wc   = w & 3;           // 0..3
    const int ln15 = lane & 15;
    const int fo8  = (lane >> 4) * 8;

    int row0, col0, nkt;
    size_t kbeg;
    if constexpr (TRI) {
        const int t = xcd_swz(blockIdx.x, NTRI8);
        int i = 0;
        while ((i + 1) * (i + 2) / 2 <= t) ++i;
        const int j = t - i * (i + 1) / 2;
        row0 = i * 256; col0 = j * 256;
        const int z = blockIdx.z;                       // 0..6, uneven chunks
        const int kb_u = z * 37 - (z > 4 ? z - 4 : 0);  // 37,37,37,37,36,36,36
        nkt = (z < 4) ? 37 : 36;
        kbeg = (size_t)kb_u * 32;
        C += ((size_t)z * NTRI8 + t) * (256 * 256);     // compact partial
    } else {
        const int s = xcd_swz(blockIdx.y * gridDim.x + blockIdx.x,
                              gridDim.x * gridDim.y);
        row0 = (s / gridDim.x) * 256;
        col0 = (s % gridDim.x) * 256;
        nkt  = Kchunk / 32;
        kbeg = (size_t)blockIdx.z * Kchunk;
        C += (size_t)blockIdx.z * Mrows * Ncols;
    }

    f32x4 acc[8][4] = {};

    // prologue: tile0's 4 units + Al(1); drain; barrier
    stage_unit(Ah_g, row0, kbeg, Ktot, lds + 0,     tid);
    stage_unit(Al_g, row0, kbeg, Ktot, lds + 8192,  tid);
    stage_unit(Bh_g, col0, kbeg, Ktot, lds + 16384, tid);
    stage_unit(Bl_g, col0, kbeg, Ktot, lds + 24576, tid);
    if (nkt > 1)
        stage_unit(Al_g, row0, kbeg + 32, Ktot, lds + 32768 + 8192, tid);
    VMCNT0();
    SBAR();

    for (int u = 0; u < nkt; ++u) {
        const int cur = (u & 1) * 32768, nxt = ((u + 1) & 1) * 32768;
        const size_t ku = kbeg + (size_t)u * 32;
        f16x8 ah[8], bh[4];

        // ---- P0: HH, n-half 0 ----
#pragma unroll
        for (int m = 0; m < 8; ++m)
            ah[m] = *(const f16x8*)&lds[cur + swz(wr * 128 + m * 16 + ln15, fo8)];
        bh[0] = *(const f16x8*)&lds[cur + 16384 + swz(wc * 64 +  0 + ln15, fo8)];
        bh[1] = *(const f16x8*)&lds[cur + 16384 + swz(wc * 64 + 16 + ln15, fo8)];
        if (u + 1 < nkt) stage_unit(Bh_g, col0, ku + 32, Ktot, lds + nxt + 16384, tid);
        SBAR();
        __builtin_amdgcn_s_setprio(1);
#pragma unroll
        for (int m = 0; m < 8; ++m) {
            acc[m][0] = MFMA16(ah[m], bh[0], acc[m][0]);
            acc[m][1] = MFMA16(ah[m], bh[1], acc[m][1]);
        }
        __builtin_amdgcn_s_setprio(0);
        SBAR();

        // ---- P1: HH, n-half 1 ----
        bh[2] = *(const f16x8*)&lds[cur + 16384 + swz(wc * 64 + 32 + ln15, fo8)];
        bh[3] = *(const f16x8*)&lds[cur + 16384 + swz(wc * 64 + 48 + ln15, fo8)];
        if (u + 1 < nkt) stage_unit(Ah_g, row0, ku + 32, Ktot, lds + nxt + 0, tid);
        SBAR();
        __builtin_amdgcn_s_setprio(1);
#pragma unroll
        for (int m = 0; m < 8; ++m) {
            acc[m][2] = MFMA16(ah[m], bh[2], acc[m][2]);
            acc[m][3] = MFMA16(ah[m], bh[3], acc[m][3]);
        }
        __builtin_amdgcn_s_setprio(0);
        SBAR();

        // ---- P2: LH, all n ----
        {
            f16x8 al[8];
#pragma unroll
            for (int m = 0; m < 8; ++m)
                al[m] = *(const f16x8*)&lds[cur + 8192 + swz(wr * 128 + m * 16 + ln15, fo8)];
            if (u + 1 < nkt) stage_unit(Bl_g, col0, ku + 32, Ktot, lds + nxt + 24576, tid);
            SBAR();
            __builtin_amdgcn_s_setprio(1);
#pragma unroll
            for (int m = 0; m < 8; ++m)
#pragma unroll
                for (int n = 0; n < 4; ++n)
                    acc[m][n] = MFMA16(al[m], bh[n], acc[m][n]);
            __builtin_amdgcn_s_setprio(0);
        }
        if (u == nkt - 1) { VMCNT0(); } else { VMCNT8(); }
        SBAR();

        // ---- P3: HL, all n ----
        if constexpr (TRI) {
            // ah LIVE from P0; no re-read (24 ds_reads/tile)
            f16x8 bl[4];
#pragma unroll
            for (int n = 0; n < 4; ++n)
                bl[n] = *(const f16x8*)&lds[cur + 24576 + swz(wc * 64 + n * 16 + ln15, fo8)];
            if (u + 2 < nkt) stage_unit(Al_g, row0, ku + 64, Ktot, lds + cur + 8192, tid);
            SBAR();
            __builtin_amdgcn_s_setprio(1);
#pragma unroll
            for (int m = 0; m < 8; ++m)
#pragma unroll
                for (int n = 0; n < 4; ++n)
                    acc[m][n] = MFMA16(ah[m], bl[n], acc[m][n]);
            __builtin_amdgcn_s_setprio(0);
        } else {
            // R0 schedule: re-read Ah into a2 (caps register pressure)
            f16x8 a2[8], bl[4];
#pragma unroll
            for (int m = 0; m < 8; ++m)
                a2[m] = *(const f16x8*)&lds[cur + swz(wr * 128 + m * 16 + ln15, fo8)];
#pragma unroll
            for (int n = 0; n < 4; ++n)
                bl[n] = *(const f16x8*)&lds[cur + 24576 + swz(wc * 64 + n * 16 + ln15, fo8)];
            if (u + 2 < nkt) stage_unit(Al_g, row0, ku + 64, Ktot, lds + cur + 8192, tid);
            SBAR();
            __builtin_amdgcn_s_setprio(1);
#pragma unroll
            for (int m = 0; m < 8; ++m)
#pragma unroll
                for (int n = 0; n < 4; ++n)
                    acc[m][n] = MFMA16(a2[m], bl[n], acc[m][n]);
            __builtin_amdgcn_s_setprio(0);
        }
        if (u < nkt - 2) { VMCNT4(); }
        else if (u == nkt - 2) { VMCNT2(); }
        SBAR();
    }

    // epilogue: C/D layout col=lane&15, row=(lane>>4)*4+reg [m89-verified]
    const int rsub = (lane >> 4) * 4;
#pragma unroll
    for (int m = 0; m < 8; ++m)
#pragma unroll
        for (int n = 0; n < 4; ++n)
#pragma unroll
            for (int r = 0; r < 4; ++r) {
                const int cr = wr * 128 + m * 16 + rsub + r;
                const int cc = wc * 64 + n * 16 + ln15;
                if constexpr (TRI)
                    C[(size_t)cr * 256 + cc] = acc[m][n][r];
                else
                    C[(size_t)(row0 + cr) * Ncols + col0 + cc] = acc[m][n][r];
            }
}

// ---------------------------------------------------------------------------
// K1: 256x256 single-product NT GEMM, BK=64, 8-phase counted-vmcnt.
// LDS per buffer: A[ks][256][32] + B[ks][256][32] (k-slice-major), 64 KiB.
// Phases: p0=(ks0,nh0) p1=(ks0,nh1) p2=(ks1,nh0) p3=(ks1,nh1).
// Stages at tile u (-> buffer u+1): p0:Ak0 p1:Bk0 p2:Ak1 p3:Bk1.
// Waits: vmcnt(4) at p1-end and p3-end (vmcnt(0) at last tile's p1).
// ---------------------------------------------------------------------------
__global__ __launch_bounds__(512, 2) void gemm8_nt(
    const f16* __restrict__ A_g, const f16* __restrict__ B_g,
    float* __restrict__ C, int Mrows, int Ncols, int Ktot, int Kchunk)
{
    __shared__ f16 lds[65536];

    const int tid  = threadIdx.x;
    const int lane = tid & 63;
    const int w    = tid >> 6;
    const int wr   = w >> 2;
    const int wc   = w & 3;
    const int ln15 = lane & 15;
    const int fo8  = (lane >> 4) * 8;

    const int s = xcd_swz(blockIdx.y * gridDim.x + blockIdx.x,
                          gridDim.x * gridDim.y);
    const int row0 = (s / gridDim.x) * 256;
    const int col0 = (s % gridDim.x) * 256;
    const int nkt  = Kchunk / 64;
    const size_t kbeg = (size_t)blockIdx.z * Kchunk;
    C += (size_t)blockIdx.z * Mrows * Ncols;

    f32x4 acc[8][4] = {};

    stage_unit(A_g, row0, kbeg,      Ktot, lds + 0,     tid);  // Ak0(0)
    stage_unit(B_g, col0, kbeg,      Ktot, lds + 16384, tid);  // Bk0(0)
    stage_unit(A_g, row0, kbeg + 32, Ktot, lds + 8192,  tid);  // Ak1(0)
    stage_unit(B_g, col0, kbeg + 32, Ktot, lds + 24576, tid);  // Bk1(0)
    VMCNT0();
    SBAR();

    for (int u = 0; u < nkt; ++u) {
        const int cur = (u & 1) * 32768, nxt = ((u + 1) & 1) * 32768;
        const size_t ku = kbeg + (size_t)u * 64;
        f16x8 a[8], b0, b1;

        // ---- p0: ks0, n-half 0 ----
#pragma unroll
        for (int m = 0; m < 8; ++m)
            a[m] = *(const f16x8*)&lds[cur + swz(wr * 128 + m * 16 + ln15, fo8)];
        b0 = *(const f16x8*)&lds[cur + 16384 + swz(wc * 64 +  0 + ln15, fo8)];
        b1 = *(const f16x8*)&lds[cur + 16384 + swz(wc * 64 + 16 + ln15, fo8)];
        if (u + 1 < nkt) stage_unit(A_g, row0, ku + 64, Ktot, lds + nxt + 0, tid);
        SBAR();
        __builtin_amdgcn_s_setprio(1);
#pragma unroll
        for (int m = 0; m < 8; ++m) {
            acc[m][0] = MFMA16(a[m], b0, acc[m][0]);
            acc[m][1] = MFMA16(a[m], b1, acc[m][1]);
        }
        __builtin_amdgcn_s_setprio(0);
        SBAR();

        // ---- p1: ks0, n-half 1 ----
        b0 = *(const f16x8*)&lds[cur + 16384 + swz(wc * 64 + 32 + ln15, fo8)];
        b1 = *(const f16x8*)&lds[cur + 16384 + swz(wc * 64 + 48 + ln15, fo8)];
        if (u + 1 < nkt) stage_unit(B_g, col0, ku + 64, Ktot, lds + nxt + 16384, tid);
        SBAR();
        __builtin_amdgcn_s_setprio(1);
#pragma unroll
        for (int m = 0; m < 8; ++m) {
            acc[m][2] = MFMA16(a[m], b0, acc[m][2]);
            acc[m][3] = MFMA16(a[m], b1, acc[m][3]);
        }
        __builtin_amdgcn_s_setprio(0);
        if (u == nkt - 1) { VMCNT0(); } else { VMCNT4(); }
        SBAR();

        // ---- p2: ks1, n-half 0 ----
#pragma unroll
        for (int m = 0; m < 8; ++m)
            a[m] = *(const f16x8*)&lds[cur + 8192 + swz(wr * 128 + m * 16 + ln15, fo8)];
        b0 = *(const f16x8*)&lds[cur + 24576 + swz(wc * 64 +  0 + ln15, fo8)];
        b1 = *(const f16x8*)&lds[cur + 24576 + swz(wc * 64 + 16 + ln15, fo8)];
        if (u + 1 < nkt) stage_unit(A_g, row0, ku + 96, Ktot, lds + nxt + 8192, tid);
        SBAR();
        __builtin_amdgcn_s_setprio(1);
#pragma unroll
        for (int m = 0; m < 8; ++m) {
            acc[m][0] = MFMA16(a[m], b0, acc[m][0]);
            acc[m][1] = MFMA16(a[m], b1, acc[m][1]);
        }
        __builtin_amdgcn_s_setprio(0);
        SBAR();

        // ---- p3: ks1, n-half 1 ----
        b0 = *(const f16x8*)&lds[cur + 24576 + swz(wc * 64 + 32 + ln15, fo8)];
        b1 = *(const f16x8*)&lds[cur + 24576 + swz(wc * 64 + 48 + ln15, fo8)];
        if (u + 1 < nkt) stage_unit(B_g, col0, ku + 96, Ktot, lds + nxt + 24576, tid);
        SBAR();
        __builtin_amdgcn_s_setprio(1);
#pragma unroll
        for (int m = 0; m < 8; ++m) {
            acc[m][2] = MFMA16(a[m], b0, acc[m][2]);
            acc[m][3] = MFMA16(a[m], b1, acc[m][3]);
        }
        __builtin_amdgcn_s_setprio(0);
        if (u < nkt - 1) { VMCNT4(); }
        SBAR();
    }

    const int rsub = (lane >> 4) * 4;
#pragma unroll
    for (int m = 0; m < 8; ++m)
#pragma unroll
        for (int n = 0; n < 4; ++n)
#pragma unroll
            for (int r = 0; r < 4; ++r)
                C[(size_t)(row0 + wr * 128 + m * 16 + rsub + r) * Ncols
                  + col0 + wc * 64 + n * 16 + ln15] = acc[m][n][r];
}

// ---------------------------------------------------------------------------
// split fp32 -> fp16 hi/lo (lo may be null), with scale folded in.
// ---------------------------------------------------------------------------
__global__ __launch_bounds__(256) void split_f32(
    const float* __restrict__ in, f16* __restrict__ hi, f16* __restrict__ lo,
    long n4, float scale)
{
    long i = (long)blockIdx.x * 256 + threadIdx.x;
    if (i >= n4) return;
    float4 x = ((const float4*)in)[i];
    float a = x.x * scale, b = x.y * scale, c = x.z * scale, d = x.w * scale;
    f16x4 h;
    h[0] = (f16)a; h[1] = (f16)b; h[2] = (f16)c; h[3] = (f16)d;
    ((f16x4*)hi)[i] = h;
    if (lo != nullptr) {
        f16x4 l;
        l[0] = (f16)(a - (float)h[0]);
        l[1] = (f16)(b - (float)h[1]);
        l[2] = (f16)(c - (float)h[2]);
        l[3] = (f16)(d - (float)h[3]);
        ((f16x4*)lo)[i] = l;
    }
}

// ---------------------------------------------------------------------------
// fused split fp32 -> f16 hi/lo (row-major) + hi^T, 64x64 tiles.
// lo may be null. Replaces split_f32 + transpose_h for X and Wk.
// ---------------------------------------------------------------------------
__global__ __launch_bounds__(256) void split_xt(
    const float* __restrict__ in, f16* __restrict__ hi, f16* __restrict__ lo,
    f16* __restrict__ hiT, int rows, int cols)
{
    __shared__ f16 tile[64][72];
    const int c0 = blockIdx.x * 64;
    const int r0 = blockIdx.y * 64;
    const int t = threadIdx.x;
    const int lr = t >> 3;      // 0..31
    const int lc8 = t & 7;      // 0..7
#pragma unroll
    for (int h = 0; h < 2; ++h) {
        const int r = lr + h * 32;
        const float* src = &in[(size_t)(r0 + r) * cols + c0 + lc8 * 8];
        float4 a = ((const float4*)src)[0];
        float4 b = ((const float4*)src)[1];
        float v[8] = {a.x, a.y, a.z, a.w, b.x, b.y, b.z, b.w};
        f16x8 hv, lv;
#pragma unroll
        for (int j = 0; j < 8; ++j) {
            hv[j] = (f16)v[j];
            lv[j] = (f16)(v[j] - (float)hv[j]);
        }
        *(f16x8*)&hi[(size_t)(r0 + r) * cols + c0 + lc8 * 8] = hv;
        if (lo != nullptr)
            *(f16x8*)&lo[(size_t)(r0 + r) * cols + c0 + lc8 * 8] = lv;
#pragma unroll
        for (int j = 0; j < 8; ++j) tile[r][lc8 * 8 + j] = hv[j];
    }
    __syncthreads();
#pragma unroll
    for (int h = 0; h < 2; ++h) {
        const int c = lr + h * 32;
        f16x8 v;
#pragma unroll
        for (int j = 0; j < 8; ++j) v[j] = tile[lc8 * 8 + j][c];
        *(f16x8*)&hiT[(size_t)(c0 + c) * rows + r0 + lc8 * 8] = v;
    }
}

// ---------------------------------------------------------------------------
// reduce 4 contiguous fp32 partials -> fp16 hi/lo (lo may be null), scaled
// ---------------------------------------------------------------------------
__global__ __launch_bounds__(256) void reduce4_split(
    const float* __restrict__ P, f16* __restrict__ hi, f16* __restrict__ lo,
    long n4, float scale)
{
    long i = (long)blockIdx.x * 256 + threadIdx.x;
    if (i >= n4) return;
    const float4* p = (const float4*)P;
    float4 a = p[i], b = p[i + n4], c = p[i + 2 * n4], d = p[i + 3 * n4];
    float v0 = ((a.x + b.x) + (c.x + d.x)) * scale;
    float v1 = ((a.y + b.y) + (c.y + d.y)) * scale;
    float v2 = ((a.z + b.z) + (c.z + d.z)) * scale;
    float v3 = ((a.w + b.w) + (c.w + d.w)) * scale;
    f16x4 h;
    h[0] = (f16)v0; h[1] = (f16)v1; h[2] = (f16)v2; h[3] = (f16)v3;
    ((f16x4*)hi)[i] = h;
    if (lo != nullptr) {
        f16x4 l;
        l[0] = (f16)(v0 - (float)h[0]);
        l[1] = (f16)(v1 - (float)h[1]);
        l[2] = (f16)(v2 - (float)h[2]);
        l[3] = (f16)(v3 - (float)h[3]);
        ((f16x4*)lo)[i] = l;
    }
}

// ---------------------------------------------------------------------------
// reduce 7 compact 256x256 triangle partials -> Ghi/Glo at tile (i,j)
// grid (64, NTRI8): 64x256 threads cover 256x256 float4s per tile
// ---------------------------------------------------------------------------
__global__ __launch_bounds__(256) void reduce7_tri(
    const float* __restrict__ P, f16* __restrict__ hi, f16* __restrict__ lo)
{
    const int t = blockIdx.y;
    int i = 0;
    while ((i + 1) * (i + 2) / 2 <= t) ++i;
    const int j = t - i * (i + 1) / 2;

    const int i4 = blockIdx.x * 256 + threadIdx.x;   // [0, 16384)
    const int r  = i4 >> 6;
    const int c4 = i4 & 63;
    const long zs = (long)NTRI8 * (256 * 256 / 4);   // slice stride in float4s
    const float4* q = (const float4*)P + (long)t * (256 * 256 / 4) + i4;

    float v0 = 0.f, v1 = 0.f, v2 = 0.f, v3 = 0.f;
#pragma unroll
    for (int z = 0; z < 7; ++z) {
        float4 a = q[z * zs];
        v0 += a.x; v1 += a.y; v2 += a.z; v3 += a.w;
    }
    f16x4 h;
    h[0] = (f16)v0; h[1] = (f16)v1; h[2] = (f16)v2; h[3] = (f16)v3;
    const size_t o = (size_t)(i * 256 + r) * DDIM + j * 256 + c4 * 4;
    *(f16x4*)&hi[o] = h;
    f16x4 l;
    l[0] = (f16)(v0 - (float)h[0]);
    l[1] = (f16)(v1 - (float)h[1]);
    l[2] = (f16)(v2 - (float)h[2]);
    l[3] = (f16)(v3 - (float)h[3]);
    *(f16x4*)&lo[o] = l;
}

// ---------------------------------------------------------------------------
// symmetrize: mirror strict-lower 64-tiles (a,b), a>b, transposed to (b,a)
// ---------------------------------------------------------------------------
__global__ __launch_bounds__(256) void symm_h(f16* __restrict__ Ghi, f16* __restrict__ Glo)
{
    const int a = blockIdx.y, b = blockIdx.x;
    if (a <= b) return;
    __shared__ f16 tile[64][72];
    const int t = threadIdx.x;
    const int lr = t >> 3, lc8 = t & 7;
    for (int q = 0; q < 2; ++q) {
        f16* G = q ? Glo : Ghi;
        const f16* src = G + ((size_t)a * 64) * DDIM + b * 64;
        f16* dst = G + ((size_t)b * 64) * DDIM + a * 64;
        if (q) __syncthreads();
#pragma unroll
        for (int h = 0; h < 2; ++h) {
            const int r = lr + h * 32;
            f16x8 v = *(const f16x8*)&src[(size_t)r * DDIM + lc8 * 8];
#pragma unroll
            for (int jj = 0; jj < 8; ++jj) tile[r][lc8 * 8 + jj] = v[jj];
        }
        __syncthreads();
#pragma unroll
        for (int h = 0; h < 2; ++h) {
            const int c = lr + h * 32;
            f16x8 v;
#pragma unroll
            for (int jj = 0; jj < 8; ++jj) v[jj] = tile[lc8 * 8 + jj][c];
            *(f16x8*)&dst[(size_t)c * DDIM + lc8 * 8] = v;
        }
    }
}

// ---------------------------------------------------------------------------
// row softmax over sum of 4 fp32 partials (each rows x n): -> Z fp16
// ---------------------------------------------------------------------------
__global__ __launch_bounds__(256) void softmax_rows4(
    const float* __restrict__ S, f16* __restrict__ Z, int n)
{
    const int row = blockIdx.x;
    const int t = threadIdx.x;
    const int lane = t & 63, wv = t >> 6;
    const long ps = (long)DDIM * DDIM;
    const float* s = S + (size_t)row * n + t * 8;

    float x[8] = {};
#pragma unroll
    for (int q = 0; q < 4; ++q) {
        float4 a = ((const float4*)(s + q * ps))[0];
        float4 b = ((const float4*)(s + q * ps))[1];
        x[0] += a.x; x[1] += a.y; x[2] += a.z; x[3] += a.w;
        x[4] += b.x; x[5] += b.y; x[6] += b.z; x[7] += b.w;
    }

    float m = x[0];
#pragma unroll
    for (int j = 1; j < 8; ++j) m = fmaxf(m, x[j]);
    for (int o = 32; o; o >>= 1) m = fmaxf(m, __shfl_xor(m, o, 64));

    __shared__ float rmax[4], rsum[4];
    if (lane == 0) rmax[wv] = m;
    __syncthreads();
    m = fmaxf(fmaxf(rmax[0], rmax[1]), fmaxf(rmax[2], rmax[3]));

    float e[8], sum = 0.f;
#pragma unroll
    for (int j = 0; j < 8; ++j) { e[j] = expf(x[j] - m); sum += e[j]; }
    for (int o = 32; o; o >>= 1) sum += __shfl_xor(sum, o, 64);
    if (lane == 0) rsum[wv] = sum;
    __syncthreads();
    sum = rsum[0] + rsum[1] + rsum[2] + rsum[3];
    const float rs = 1.0f / sum;

    f16x8 z;
#pragma unroll
    for (int j = 0; j < 8; ++j) z[j] = (f16)(e[j] * rs);
    *(f16x8*)&Z[(size_t)row * n + t * 8] = z;
}

// ---------------------------------------------------------------------------
extern "C" void kernel_launch(void* const* d_in, const int* in_sizes, int n_in,
                              void* d_out, int out_size, void* d_ws, size_t ws_size,
                              hipStream_t stream)
{
    const float* X  = (const float*)d_in[0];  // (D, N)
    const float* Wq = (const float*)d_in[1];  // (D, D)
    const float* Wk = (const float*)d_in[2];  // (D, D)  -> V projection (ref swap)
    const float* Wv = (const float*)d_in[3];  // (D, D)  -> K projection (ref swap)
    float* out = (float*)d_out;
    char* ws = (char*)d_ws;

    const size_t MiB = 1024 * 1024;
    const size_t NEED = 184 * MiB;
    if (ws_size < NEED) return;  // diagnostic: output stays zero -> absmax == max|ref|

    // layout (MiB offsets), lifetimes:
    f16*   Xhi   = (f16*)(ws + 0 * MiB);     // dead after G-GEMM
    f16*   Xlo   = (f16*)(ws + 32 * MiB);    // dead after G-GEMM
    f16*   XhiT  = (f16*)(ws + 64 * MiB);    // live to the end (out-GEMM B)
    float* P     = (float*)(ws + 96 * MiB);  // [96,160): G tri partials (7x9MiB) / dense 4x16MiB
    f16*   Ghi   = (f16*)(ws + 160 * MiB);   // dead after M1-GEMM
    f16*   Glo   = (f16*)(ws + 168 * MiB);   // dead after M1-GEMM
    f16*   Z     = (f16*)(ws + 176 * MiB);
    // carved from dead X region after G-GEMM:
    f16*   Wqhi  = (f16*)(ws + 0 * MiB);
    f16*   Wqlo  = (f16*)(ws + 8 * MiB);
    f16*   Wvhi  = (f16*)(ws + 16 * MiB);
    f16*   Wvlo  = (f16*)(ws + 24 * MiB);
    f16*   Wkhi  = (f16*)(ws + 32 * MiB);
    f16*   WkhiT = (f16*)(ws + 40 * MiB);
    f16*   M1hi  = (f16*)(ws + 48 * MiB);
    f16*   M1lo  = (f16*)(ws + 56 * MiB);
    f16*   ZWkhi = (f16*)(ws + 0 * MiB);     // reuses Wqhi (dead after M1-GEMM)

    const float scale = 0.022097086912079608f;  // 1/sqrt(2048)
    const long n4W = (long)DDIM * DDIM / 4;

    // split X + transpose fused (writes Xhi, Xlo, XhiT in one pass)
    split_xt<<<dim3(NDIM / 64, DDIM / 64), 256, 0, stream>>>(
        X, Xhi, Xlo, XhiT, DDIM, NDIM);

    // G = X X^T lower triangle: 36 256^2 tiles x 7 uneven K-slices = 252 blocks
    gemm8_split<true><<<dim3(NTRI8, 1, 7), 512, 0, stream>>>(
        Xhi, Xlo, Xhi, Xlo, P, DDIM, DDIM, NDIM, 0);
    reduce7_tri<<<dim3(64, NTRI8), 256, 0, stream>>>(P, Ghi, Glo);
    symm_h<<<dim3(32, 32), 256, 0, stream>>>(Ghi, Glo);

    // W splits (X regions now dead); Wk split+transpose fused
    split_f32<<<dim3(n4W / 256), 256, 0, stream>>>(Wq, Wqhi, Wqlo, n4W, 1.0f);
    split_f32<<<dim3(n4W / 256), 256, 0, stream>>>(Wv, Wvhi, Wvlo, n4W, 1.0f);
    split_xt<<<dim3(DDIM / 64, DDIM / 64), 256, 0, stream>>>(
        Wk, Wkhi, (f16*)nullptr, WkhiT, DDIM, DDIM);

    // M1 = Wq G (G symmetric -> NT works), fused split, split-K x4
    gemm8_split<false><<<dim3(8, 8, 4), 512, 0, stream>>>(
        Wqhi, Wqlo, Ghi, Glo, P, DDIM, DDIM, DDIM, DDIM / 4);
    reduce4_split<<<dim3(n4W / 256), 256, 0, stream>>>(P, M1hi, M1lo, n4W, scale);

    // S = (M1*scale) Wv^T, fused split, split-K x4 (softmax consumes partials)
    gemm8_split<false><<<dim3(8, 8, 4), 512, 0, stream>>>(
        M1hi, M1lo, Wvhi, Wvlo, P, DDIM, DDIM, DDIM, DDIM / 4);
    softmax_rows4<<<dim3(DDIM), 256, 0, stream>>>(P, Z, DDIM);

    // ZWk = Z Wk (NT with B = Wk^T), split-K x4, then collapse to fp16
    gemm8_nt<<<dim3(8, 8, 4), 512, 0, stream>>>(
        Z, WkhiT, P, DDIM, DDIM, DDIM, DDIM / 4);
    reduce4_split<<<dim3(n4W / 256), 256, 0, stream>>>(P, ZWkhi, (f16*)nullptr, n4W, 1.0f);

    // out = (Z Wk) X  (NT: A=ZWkhi (D x D), B=XhiT (N x D))
    gemm8_nt<<<dim3(32, 8, 1), 512, 0, stream>>>(
        ZWkhi, XhiT, out, DDIM, NDIM, DDIM, DDIM);
}